// Round 3
// baseline (495.515 us; speedup 1.0000x reference)
//
#include <hip/hip_runtime.h>

#define NA 8192   // atoms
#define NB 8192   // bonds
#define CH 2048   // LJ streaming chunk (floats per matrix per buffer)

// ---------- pack x[N,3] -> float4[N] (xyz + sq) in workspace ----------
// sq must replicate numpy's np.sum(x*x, axis=1) rounding: plain RN mults,
// sequential adds ((x^2 + y^2) + z^2). __f*_rn blocks fp-contract fusion.
__global__ void pack_x_kernel(const float* __restrict__ x, float4* __restrict__ x4, int n) {
    int t = blockIdx.x * blockDim.x + threadIdx.x;
    if (t < n) {
        float a = x[3 * t + 0], b = x[3 * t + 1], c = x[3 * t + 2];
        float sq = __fadd_rn(__fadd_rn(__fmul_rn(a, a), __fmul_rn(b, b)), __fmul_rn(c, c));
        x4[t] = make_float4(a, b, c, sq);
    }
}

// ---------- reduction helper: wave shuffle -> LDS -> one atomic ----------
__device__ __forceinline__ void block_reduce_atomic(float v, float* __restrict__ out) {
#pragma unroll
    for (int off = 32; off > 0; off >>= 1) v += __shfl_down(v, off);
    __shared__ float smem[8];
    const int lane = threadIdx.x & 63;
    const int wave = threadIdx.x >> 6;
    if (lane == 0) smem[wave] = v;
    __syncthreads();
    if (threadIdx.x == 0) {
        float s = 0.0f;
        const int nw = (int)(blockDim.x >> 6);
        for (int w = 0; w < nw; ++w) s += smem[w];
        atomicAdd(out, s);
    }
}

// ---------- bond term (magnitude ~1e9; simple) ----------
__global__ void bond_kernel(const float* __restrict__ x, const int* __restrict__ pairs,
                            const float* __restrict__ kb, const float* __restrict__ b0,
                            float* __restrict__ out) {
    int t = blockIdx.x * blockDim.x + threadIdx.x;
    float v = 0.0f;
    if (t < NB) {
        int i = pairs[2 * t + 0] & (NA - 1);
        int j = pairs[2 * t + 1] & (NA - 1);
        float dx = __fsub_rn(x[3 * i + 0], x[3 * j + 0]);
        float dy = __fsub_rn(x[3 * i + 1], x[3 * j + 1]);
        float dz = __fsub_rn(x[3 * i + 2], x[3 * j + 2]);
        float ss = __fadd_rn(__fadd_rn(__fmul_rn(dx, dx), __fmul_rn(dy, dy)), __fmul_rn(dz, dz));
        float dis = __fsqrt_rn(ss);
        float d = __fsub_rn(dis, b0[t]);
        v = __fmul_rn(kb[t], __fmul_rn(d, d));
    }
    block_reduce_atomic(v, out);
}

// ---------- LJ pair energy, replicating the reference's Gram-form rounding ----
// DO NOT CHANGE the operation sequence here — bit-compat with reference.
__device__ __forceinline__ float lj_pair(const float4 xi, const float4 xj,
                                         const float e, const float rm) {
    float dot = fmaf(xi.z, xj.z, fmaf(xi.y, xj.y, __fmul_rn(xi.x, xj.x)));
    float t   = __fadd_rn(xi.w, xj.w);          // sq_i + sq_j
    float d2  = fmaf(-2.0f, dot, t);            // == RN(t - 2*dot), 2*dot exact
    d2 = fmaxf(d2, 0.0f);
    float dist = (d2 > 0.0f) ? __fsqrt_rn(d2) : 0.0f;
    float rod  = __fdiv_rn(rm, dist);
    float r2 = __fmul_rn(rod, rod);
    float r6 = __fmul_rn(__fmul_rn(r2, r2), r2);
    return __fmul_rn(e, __fsub_rn(__fmul_rn(r6, r6), __fmul_rn(2.0f, r6)));
}

// ---------- all-pairs LJ, strict upper triangle, LDS-staged double-buffer ----
// grid = NA/2 blocks; block b handles rows b and NA-1-b => exactly NA-1 pairs/block.
// Streaming pipeline (T14 issue-early/write-late): eps/rmin are consumed from
// LDS; the global float4 loads for chunk c+1 are ISSUED before compute of
// chunk c, so HBM latency (~900 cyc) hides under compute. Round-0/1 plain
// loops drain vmcnt every iteration (no cross-iteration MLP) — this is the
// hypothesized 3.5x-off-roofline cause. LDS 32 KB/block -> 5 blocks/CU.
// All __syncthreads() sit under block-uniform control flow (i, c0, havenext
// derive from blockIdx only) — audited for divergent-barrier hangs.
__global__ __launch_bounds__(256) void lj_kernel(const float4* __restrict__ x4,
                                                 const float* __restrict__ eps,
                                                 const float* __restrict__ rmin,
                                                 float* __restrict__ out) {
    const int N = NA;
    __shared__ float se[2][CH];
    __shared__ float sm[2][CH];
    float acc = 0.0f;
    const int tid = (int)threadIdx.x;
    const int rowA = (int)blockIdx.x;

    float4 ea, eb, ma, mb;   // staged registers (one chunk in flight)

#pragma unroll 1
    for (int r = 0; r < 2; ++r) {
        const int i = (r == 0) ? rowA : (N - 1 - rowA);   // block-uniform
        const float4 xi = x4[i];
        const float* __restrict__ erow = eps + (size_t)i * N;
        const float* __restrict__ rrow = rmin + (size_t)i * N;
        const int c0 = (i + 1) & ~3;   // 16B-aligned chunk origin
        if (c0 >= N) continue;         // row N-1: nothing to do (uniform branch)

        // Tails: chunk loads may run past column N into the next row of the
        // same matrix — always inside the allocation (worst case i=N-2:
        // i*N + 8188 + 2047 < N*N). Garbage is discarded by the j<N guard.

#define LOADCHUNK(cc) do {                                            \
            const float4* __restrict__ e4 = (const float4*)(erow + (cc)); \
            const float4* __restrict__ m4 = (const float4*)(rrow + (cc)); \
            ea = e4[tid]; eb = e4[tid + 256];                          \
            ma = m4[tid]; mb = m4[tid + 256];                          \
        } while (0)

#define WRITE_LDS(b) do {                                             \
            ((float4*)se[b])[tid] = ea; ((float4*)se[b])[tid + 256] = eb; \
            ((float4*)sm[b])[tid] = ma; ((float4*)sm[b])[tid + 256] = mb; \
        } while (0)

#define COMPUTE(b, cbase) do {                                        \
            _Pragma("unroll")                                         \
            for (int k = 0; k < CH / 256; ++k) {                      \
                const int j = (cbase) + k * 256 + tid;                \
                if (j < N) {                                          \
                    const float e = se[b][k * 256 + tid];             \
                    const float m = sm[b][k * 256 + tid];             \
                    const float v = lj_pair(xi, x4[j], e, m);         \
                    acc += (j > i) ? v : 0.0f;                        \
                }                                                     \
            }                                                         \
        } while (0)

        int c = c0;
        LOADCHUNK(c);
        WRITE_LDS(0);
        int nxt = c + CH;
        bool havenext = (nxt < N);
        if (havenext) LOADCHUNK(nxt);   // issue-early: in flight across compute
        __syncthreads();
        int cur = 0;
        while (true) {
            COMPUTE(cur, c);
            if (!havenext) break;
            __syncthreads();            // all waves done reading buf[cur^1]
            WRITE_LDS(cur ^ 1);         // write-late: regs -> LDS
            c = nxt;
            nxt = c + CH;
            havenext = (nxt < N);
            if (havenext) LOADCHUNK(nxt);
            __syncthreads();
            cur ^= 1;
        }
        __syncthreads();                // LDS reused by next row
#undef LOADCHUNK
#undef WRITE_LDS
#undef COMPUTE
    }
    block_reduce_atomic(acc, out);
}

extern "C" void kernel_launch(void* const* d_in, const int* in_sizes, int n_in,
                              void* d_out, int out_size, void* d_ws, size_t ws_size,
                              hipStream_t stream) {
    const float* x     = (const float*)d_in[0];
    const int*   pairs = (const int*)d_in[1];
    const float* kb    = (const float*)d_in[2];
    const float* b0    = (const float*)d_in[3];
    const float* eps   = (const float*)d_in[4];
    const float* rmin  = (const float*)d_in[5];
    float* out = (float*)d_out;
    float4* x4 = (float4*)d_ws;   // needs NA*16 = 128 KB of workspace

    hipMemsetAsync(out, 0, sizeof(float), stream);
    pack_x_kernel<<<(NA + 255) / 256, 256, 0, stream>>>(x, x4, NA);
    bond_kernel<<<(NB + 255) / 256, 256, 0, stream>>>(x, pairs, kb, b0, out);
    lj_kernel<<<NA / 2, 256, 0, stream>>>(x4, eps, rmin, out);
}